// Round 9
// baseline (173.276 us; speedup 1.0000x reference)
//
#include <hip/hip_runtime.h>

#define BB 4
#define TT 2048
#define DD 1024
#define SCALE 32.0f
#define NTILE 136   // 128x128 lower-tri tiles per batch
#define L2E 1.4426950408889634f

typedef _Float16 f16;
typedef __attribute__((ext_vector_type(4))) _Float16 half4v;
typedef __attribute__((ext_vector_type(8))) _Float16 half8v;
typedef __attribute__((ext_vector_type(16))) float f32x16;

typedef const __attribute__((address_space(1))) unsigned int* gas_u32;
typedef __attribute__((address_space(3))) unsigned int* las_u32;

static __device__ inline void gload16(const void* g, void* l) {
    __builtin_amdgcn_global_load_lds((gas_u32)g, (las_u32)l, 16, 0, 0);
}

static __device__ inline half8v ld_frag(const f16* p) {
    half4v a = *(const half4v*)p;
    half4v b = *(const half4v*)(p + 4);
    half8v r;
    r[0] = a[0]; r[1] = a[1]; r[2] = a[2]; r[3] = a[3];
    r[4] = b[0]; r[5] = b[1]; r[6] = b[2]; r[7] = b[3];
    return r;
}

// ===========================================================================
// Slot-major granules (8 KiB each), conflict-free ds_read_b128 by design:
//   Qt/Kt granule (b, mi, ck16):  byte = s*2048 + r*16   (s 0-1 hi, 2-3 lo)
//   Pt granule (b, mi, ck32):     byte = s*2048 + r*16, k = ck*32+s*8+e
//   Vt granule (b, nj, ck32):     byte = s*2048 + n*16, k = ck*32+s*8+e
// Fused softmax: k1 writes P_t = exp(v - m_tile) (f16) + per-tile stats
// (m_t, l_t); k2 scales A-fragments by exp(m_t - m_row)/l_row.
// ===========================================================================

// --- prep: merged repack(Q,K) + transpose(V) (proven) ----------------------
__global__ __launch_bounds__(256) void prep(const float* __restrict__ Q,
                                            const float* __restrict__ K,
                                            const float* __restrict__ V,
                                            f16* __restrict__ Qt,
                                            f16* __restrict__ Kt,
                                            f16* __restrict__ Vt) {
    __shared__ char plds[33024];
    int bid = blockIdx.x;
    int tid = threadIdx.x;
    if (bid < 2048) {
        char* rl = plds;
        int which = bid >> 10, b = (bid >> 8) & 3, mi = (bid >> 4) & 15, ks4 = bid & 15;
        const float* src = which ? K : Q;
        f16* dst = which ? Kt : Qt;
        float sc = which ? 1.0f : SCALE;
        int r = tid >> 1, h = tid & 1;
        const float* p = src + ((size_t)(b * TT + mi * 128 + r)) * DD + ks4 * 64 + h * 32;
#pragma unroll
        for (int j = 0; j < 4; ++j) {
            float4 x0 = *(const float4*)(p + j * 8);
            float4 x1 = *(const float4*)(p + j * 8 + 4);
            float vv[8] = {x0.x, x0.y, x0.z, x0.w, x1.x, x1.y, x1.z, x1.w};
            half8v hi, lo;
#pragma unroll
            for (int e = 0; e < 8; ++e) {
                float x = vv[e] * sc;
                f16 hh = (f16)x;
                hi[e] = hh;
                lo[e] = (f16)(x - (float)hh);
            }
            int ckl = h * 2 + (j >> 1);
            int shalf = j & 1;
            *(half8v*)(rl + ckl * 8192 + shalf * 2048 + r * 16) = hi;
            *(half8v*)(rl + ckl * 8192 + (2 + shalf) * 2048 + r * 16) = lo;
        }
        __syncthreads();
        char* gout = (char*)dst + ((size_t)((b * 16 + mi) * 64 + ks4 * 4)) * 8192 + tid * 128;
#pragma unroll
        for (int q = 0; q < 8; ++q)
            *(float4*)(gout + q * 16) = *(float4*)(rl + tid * 128 + q * 16);
    } else {
        float (*Vs)[129] = (float(*)[129])plds;
        int bid2 = bid - 2048;
        int b = bid2 >> 8, kb = (bid2 >> 3) & 31, nj = bid2 & 7;
        const float* src = V + ((size_t)(b * TT + kb * 64)) * DD + nj * 128;
#pragma unroll
        for (int it = 0; it < 8; ++it) {
            int f4 = it * 256 + tid;
            int row = f4 >> 5, c4 = f4 & 31;
            float4 x = *(const float4*)(src + (size_t)row * DD + c4 * 4);
            Vs[row][c4 * 4 + 0] = x.x;
            Vs[row][c4 * 4 + 1] = x.y;
            Vs[row][c4 * 4 + 2] = x.z;
            Vs[row][c4 * 4 + 3] = x.w;
        }
        __syncthreads();
#pragma unroll
        for (int qq = 0; qq < 4; ++qq) {
            int q = tid * 4 + qq;
            int ckl = q >> 9, s = (q >> 7) & 3, n = q & 127;
            half8v hv;
#pragma unroll
            for (int e = 0; e < 8; ++e) hv[e] = (f16)Vs[ckl * 32 + s * 8 + e][n];
            char* out = (char*)Vt + ((size_t)((b * 8 + nj) * 64 + kb * 2 + ckl)) * 8192
                        + s * 2048 + n * 16;
            *(half8v*)out = hv;
        }
    }
}

// --- K1: proven 67.3us loop + fused tile-softmax epilogue ------------------
__global__ __launch_bounds__(256, 3) void k1_qk9(const f16* __restrict__ Qt,
                                                 const f16* __restrict__ Kt,
                                                 f16* __restrict__ Pt,
                                                 float2* __restrict__ stats) {
    __shared__ char lds[32768];   // 2 bufs x (A 8K | B 8K); reused in epilogue

    int bid0 = blockIdx.x;
    int bid = (bid0 & 7) * (BB * NTILE / 8) + (bid0 >> 3);   // XCD swizzle
    int b = bid / NTILE, rr0 = bid % NTILE;
    int mi = 0;
    while ((mi + 1) * (mi + 2) / 2 <= rr0) ++mi;
    int nj = rr0 - mi * (mi + 1) / 2;

    const char* Abase = (const char*)Qt + ((size_t)((b * 16 + mi) * 64)) * 8192;
    const char* Bbase = (const char*)Kt + ((size_t)((b * 16 + nj) * 64)) * 8192;
    char* Ptb = (char*)Pt + ((size_t)((b * 16 + mi) * 64 + nj * 4)) * 8192;

    int tid = threadIdx.x;
    int lane = tid & 63;
    int wv = tid >> 6;
    int l31 = lane & 31, lhi = lane >> 5;
    int wrow = wv >> 1, wcol = wv & 1;

    int aoff[2], boff[2];
#pragma unroll
    for (int f = 0; f < 2; ++f) {
        int ra = wrow * 64 + f * 32 + l31;
        int rb = wcol * 64 + f * 32 + l31;
        aoff[f] = lhi * 2048 + ra * 16;
        boff[f] = lhi * 2048 + rb * 16;
    }
    int lane_go = wv * 2048 + lane * 16;
    int lane_lo = wv * 2048;

    f32x16 acc[2][2] = {};

#define K1_STAGE(CK, BUF)                                                       \
    {                                                                           \
        const char* ga = Abase + (size_t)(CK) * 8192 + lane_go;                 \
        const char* gb = Bbase + (size_t)(CK) * 8192 + lane_go;                 \
        char* la = lds + (BUF) * 16384 + lane_lo;                               \
        char* lb = la + 8192;                                                   \
        gload16(ga, la);                                                        \
        gload16(ga + 1024, la + 1024);                                          \
        gload16(gb, lb);                                                        \
        gload16(gb + 1024, lb + 1024);                                          \
    }

    K1_STAGE(0, 0);
    int cur = 0;
    for (int ck = 0; ck < 64; ++ck) {
        __syncthreads();
        if (ck + 1 < 64) K1_STAGE(ck + 1, cur ^ 1);
        const char* As = lds + cur * 16384;
        const char* Bs = As + 8192;
        half8v ah[2], al[2], bh[2], bl[2];
#pragma unroll
        for (int f = 0; f < 2; ++f) {
            ah[f] = *(const half8v*)(As + aoff[f]);
            al[f] = *(const half8v*)(As + aoff[f] + 4096);
            bh[f] = *(const half8v*)(Bs + boff[f]);
            bl[f] = *(const half8v*)(Bs + boff[f] + 4096);
        }
#pragma unroll
        for (int fm = 0; fm < 2; ++fm)
#pragma unroll
            for (int fn = 0; fn < 2; ++fn) {
                acc[fm][fn] = __builtin_amdgcn_mfma_f32_32x32x16_f16(ah[fm], bh[fn], acc[fm][fn], 0, 0, 0);
                acc[fm][fn] = __builtin_amdgcn_mfma_f32_32x32x16_f16(ah[fm], bl[fn], acc[fm][fn], 0, 0, 0);
                acc[fm][fn] = __builtin_amdgcn_mfma_f32_32x32x16_f16(al[fm], bh[fn], acc[fm][fn], 0, 0, 0);
            }
        cur ^= 1;
    }
#undef K1_STAGE

    // ---- fused tile softmax epilogue ----
    __syncthreads();                           // all LDS reads done
    float* mpart = (float*)lds;                // [2][128]
    float* spart = (float*)(lds + 1024);       // [2][128]
    bool diag = (nj == mi);

    // pass 1: per-row (this wave's 64 cols) masked max -> mpart[wcol][lrow]
#pragma unroll
    for (int fm = 0; fm < 2; ++fm)
#pragma unroll
        for (int g = 0; g < 16; ++g) {
            int rr = (g & 3) + 8 * (g >> 2) + 4 * lhi;
            int lrow = wrow * 64 + fm * 32 + rr;
            float v0 = acc[fm][0][g], v1 = acc[fm][1][g];
            if (diag) {
                if (wcol * 64 + l31 > lrow) v0 = -3.0e38f;
                if (wcol * 64 + 32 + l31 > lrow) v1 = -3.0e38f;
            }
            float mv = fmaxf(v0, v1);
#pragma unroll
            for (int o = 16; o > 0; o >>= 1) mv = fmaxf(mv, __shfl_xor(mv, o));
            if (l31 == 0) mpart[wcol * 128 + lrow] = mv;
        }
    __syncthreads();

    // pass 2: combined tile max, exp, write P, partial sums -> spart
#pragma unroll
    for (int fm = 0; fm < 2; ++fm)
#pragma unroll
        for (int g = 0; g < 16; ++g) {
            int rr = (g & 3) + 8 * (g >> 2) + 4 * lhi;
            int lrow = wrow * 64 + fm * 32 + rr;
            float mt = fmaxf(mpart[lrow], mpart[128 + lrow]);
            float sum = 0.f;
#pragma unroll
            for (int fn = 0; fn < 2; ++fn) {
                float v = acc[fm][fn][g];
                bool msk = diag && (wcol * 64 + fn * 32 + l31 > lrow);
                float ev = msk ? 0.f : exp2f((v - mt) * L2E);
                sum += ev;
                int ckl = wcol * 2 + fn;
                int s = l31 >> 3, el = l31 & 7;
                *(f16*)(Ptb + ckl * 8192 + s * 2048 + lrow * 16 + el * 2) = (f16)ev;
            }
#pragma unroll
            for (int o = 16; o > 0; o >>= 1) sum += __shfl_xor(sum, o);
            if (l31 == 0) spart[wcol * 128 + lrow] = sum;
        }
    __syncthreads();

    // pass 3: combine halves, store per-tile stats
    if (tid < 128) {
        float mt = fmaxf(mpart[tid], mpart[128 + tid]);
        float lt = spart[tid] + spart[128 + tid];
        float2 st; st.x = mt; st.y = lt;
        stats[((size_t)((b * 16 + mi) * 16 + nj)) * 128 + tid] = st;
    }
}

// --- K2: BK=64 dbuf + per-row per-tile softmax factors ---------------------
__global__ __launch_bounds__(256, 2) void k2_pv9(const f16* __restrict__ Pt,
                                                 const f16* __restrict__ Vt,
                                                 const float2* __restrict__ stats,
                                                 float* __restrict__ O) {
    __shared__ char lds[65536];       // 2 bufs x (A 16K | B 16K)
    __shared__ float ftab[16][128];   // factor[tile][local row]

    int bid0 = blockIdx.x;
    int bid = (bid0 & 7) * 64 + (bid0 >> 3);    // XCD swizzle (512 blocks)
    int b = bid >> 7, mi = (bid >> 3) & 15, nj = bid & 7;
    int kch = 2 * (mi + 1);                     // BK=64 chunks

    const char* Abase = (const char*)Pt + ((size_t)((b * 16 + mi) * 64)) * 8192;
    const char* Bbase = (const char*)Vt + ((size_t)((b * 8 + nj) * 64)) * 8192;
    float* Ob = O + (size_t)b * TT * DD + (size_t)(mi * 128) * DD + nj * 128;

    int tid = threadIdx.x;
    int lane = tid & 63;
    int wv = tid >> 6;
    int l31 = lane & 31, lhi = lane >> 5;
    int wrow = wv >> 1, wcol = wv & 1;
    int lane16 = lane * 16;

    int arow[2], brow[2];
#pragma unroll
    for (int f = 0; f < 2; ++f) {
        arow[f] = (wrow * 64 + f * 32 + l31) * 16;
        brow[f] = (wcol * 64 + f * 32 + l31) * 16;
    }

    f32x16 acc[2][2] = {};

#define K2_STAGE(CK, BUF)                                                       \
    {                                                                           \
        const char* ga = Abase + (size_t)(CK) * 16384 + wv * 4096 + lane16;     \
        const char* gb = Bbase + (size_t)(CK) * 16384 + wv * 4096 + lane16;     \
        char* la = lds + (BUF) * 32768 + wv * 4096;                             \
        char* lb = la + 16384;                                                  \
        gload16(ga, la);                                                        \
        gload16(ga + 1024, la + 1024);                                          \
        gload16(ga + 2048, la + 2048);                                          \
        gload16(ga + 3072, la + 3072);                                          \
        gload16(gb, lb);                                                        \
        gload16(gb + 1024, lb + 1024);                                          \
        gload16(gb + 2048, lb + 2048);                                          \
        gload16(gb + 3072, lb + 3072);                                          \
    }

    K2_STAGE(0, 0);
    if (kch > 1) K2_STAGE(1, 1);

    // factor table: ftab[t][r] = exp(m_t - m_row) / l_row
    int nt = mi + 1;
    if (tid < 128) {
        const float2* sp = stats + ((size_t)(b * 16 + mi) * 16) * 128 + tid;
        float m = -3.0e38f;
        for (int t = 0; t < nt; ++t) m = fmaxf(m, sp[(size_t)t * 128].x);
        float l = 0.f;
        for (int t = 0; t < nt; ++t) {
            float2 s = sp[(size_t)t * 128];
            l += s.y * exp2f((s.x - m) * L2E);
        }
        float invl = 1.0f / l;
        for (int t = 0; t < nt; ++t) {
            float2 s = sp[(size_t)t * 128];
            ftab[t][tid] = exp2f((s.x - m) * L2E) * invl;
        }
    }
    __syncthreads();

    int cur = 0;
    for (int it = 0; it < kch; ++it) {
        __syncthreads();
        if (it + 1 < kch) {
            int nx = it + 1;
            K2_STAGE(nx, cur ^ 1);
        }
        int t = it >> 1;
        f16 h0 = (f16)ftab[t][wrow * 64 + l31];
        f16 h1 = (f16)ftab[t][wrow * 64 + 32 + l31];
        const char* As = lds + cur * 32768;
        const char* Bs = As + 16384;
#pragma unroll
        for (int j = 0; j < 4; ++j) {
            int slotbase = (j >> 1) * 8192 + ((j & 1) * 2 + lhi) * 2048;
            half8v a0 = *(const half8v*)(As + slotbase + arow[0]);
            half8v a1 = *(const half8v*)(As + slotbase + arow[1]);
#pragma unroll
            for (int e2 = 0; e2 < 8; ++e2) { a0[e2] *= h0; a1[e2] *= h1; }
            half8v b0 = *(const half8v*)(Bs + slotbase + brow[0]);
            half8v b1 = *(const half8v*)(Bs + slotbase + brow[1]);
            acc[0][0] = __builtin_amdgcn_mfma_f32_32x32x16_f16(a0, b0, acc[0][0], 0, 0, 0);
            acc[0][1] = __builtin_amdgcn_mfma_f32_32x32x16_f16(a0, b1, acc[0][1], 0, 0, 0);
            acc[1][0] = __builtin_amdgcn_mfma_f32_32x32x16_f16(a1, b0, acc[1][0], 0, 0, 0);
            acc[1][1] = __builtin_amdgcn_mfma_f32_32x32x16_f16(a1, b1, acc[1][1], 0, 0, 0);
        }
        cur ^= 1;
    }
#undef K2_STAGE
#pragma unroll
    for (int fm = 0; fm < 2; ++fm)
#pragma unroll
        for (int fn = 0; fn < 2; ++fn)
#pragma unroll
            for (int g = 0; g < 16; ++g) {
                int rr = (g & 3) + 8 * (g >> 2) + 4 * lhi;
                int row = wrow * 64 + fm * 32 + rr;
                int col = wcol * 64 + fn * 32 + l31;
                Ob[(size_t)row * DD + col] = acc[fm][fn][g];
            }
}

// ===========================================================================
// FALLBACK (ws >= 96 MiB): r1 kernels, proven correct
// ===========================================================================
__global__ __launch_bounds__(256, 2) void k1_qk(const float* __restrict__ Q,
                                                const float* __restrict__ Kmat,
                                                float* __restrict__ S) {
    __shared__ f16 Ah[128][36], Al[128][36], Bh[128][36], Bl[128][36];
    int bid = blockIdx.x;
    int b = bid / NTILE, r = bid % NTILE;
    int mi = 0;
    while ((mi + 1) * (mi + 2) / 2 <= r) ++mi;
    int nj = r - mi * (mi + 1) / 2;
    const float* Qb = Q + ((size_t)b * TT + (size_t)mi * 128) * DD;
    const float* Kb = Kmat + ((size_t)b * TT + (size_t)nj * 128) * DD;
    float* Sb = S + (size_t)b * TT * TT + (size_t)(mi * 128) * TT + nj * 128;
    int tid = threadIdx.x;
    int lane = tid & 63;
    int wave = tid >> 6;
    int l31 = lane & 31, lhi = lane >> 5;
    int wrow = wave >> 1, wcol = wave & 1;
    int r0 = tid >> 1;
    int c0 = (tid & 1) * 16;
    f32x16 acc[2][2] = {};
    float4 abuf[4], bbuf[4];
#pragma unroll
    for (int j = 0; j < 4; ++j) {
        abuf[j] = *(const float4*)(Qb + (size_t)r0 * DD + c0 + 4 * j);
        bbuf[j] = *(const float4*)(Kb + (size_t)r0 * DD + c0 + 4 * j);
    }
    for (int ch = 0; ch < DD / 32; ++ch) {
        __syncthreads();
#pragma unroll
        for (int j = 0; j < 4; ++j) {
            float4 a = abuf[j], bq = bbuf[j];
            float ax[4] = {a.x * SCALE, a.y * SCALE, a.z * SCALE, a.w * SCALE};
            float bx[4] = {bq.x, bq.y, bq.z, bq.w};
            half4v ahv, alv, bhv, blv;
#pragma unroll
            for (int e = 0; e < 4; ++e) {
                f16 h = (f16)ax[e];
                ahv[e] = h;
                alv[e] = (f16)(ax[e] - (float)h);
                f16 g = (f16)bx[e];
                bhv[e] = g;
                blv[e] = (f16)(bx[e] - (float)g);
            }
            *(half4v*)&Ah[r0][c0 + 4 * j] = ahv;
            *(half4v*)&Al[r0][c0 + 4 * j] = alv;
            *(half4v*)&Bh[r0][c0 + 4 * j] = bhv;
            *(half4v*)&Bl[r0][c0 + 4 * j] = blv;
        }
        __syncthreads();
        if (ch + 1 < DD / 32) {
            int ck = (ch + 1) * 32;
#pragma unroll
            for (int j = 0; j < 4; ++j) {
                abuf[j] = *(const float4*)(Qb + (size_t)r0 * DD + ck + c0 + 4 * j);
                bbuf[j] = *(const float4*)(Kb + (size_t)r0 * DD + ck + c0 + 4 * j);
            }
        }
#pragma unroll
        for (int ks = 0; ks < 2; ++ks) {
            int kb = ks * 16 + lhi * 8;
            half8v ahf[2], alf[2], bhf[2], blf[2];
#pragma unroll
            for (int f = 0; f < 2; ++f) {
                ahf[f] = ld_frag(&Ah[wrow * 64 + f * 32 + l31][kb]);
                alf[f] = ld_frag(&Al[wrow * 64 + f * 32 + l31][kb]);
                bhf[f] = ld_frag(&Bh[wcol * 64 + f * 32 + l31][kb]);
                blf[f] = ld_frag(&Bl[wcol * 64 + f * 32 + l31][kb]);
            }
#pragma unroll
            for (int fm = 0; fm < 2; ++fm)
#pragma unroll
                for (int fn = 0; fn < 2; ++fn) {
                    acc[fm][fn] = __builtin_amdgcn_mfma_f32_32x32x16_f16(ahf[fm], bhf[fn], acc[fm][fn], 0, 0, 0);
                    acc[fm][fn] = __builtin_amdgcn_mfma_f32_32x32x16_f16(ahf[fm], blf[fn], acc[fm][fn], 0, 0, 0);
                    acc[fm][fn] = __builtin_amdgcn_mfma_f32_32x32x16_f16(alf[fm], bhf[fn], acc[fm][fn], 0, 0, 0);
                }
        }
    }
#pragma unroll
    for (int fm = 0; fm < 2; ++fm)
#pragma unroll
        for (int fn = 0; fn < 2; ++fn)
#pragma unroll
            for (int g = 0; g < 16; ++g) {
                int rr = (g & 3) + 8 * (g >> 2) + 4 * lhi;
                int row = wrow * 64 + fm * 32 + rr;
                int col = wcol * 64 + fn * 32 + l31;
                Sb[(size_t)row * TT + col] = acc[fm][fn][g];
            }
}

__global__ __launch_bounds__(256) void k1b_softmax(const float* __restrict__ S,
                                                   f16* __restrict__ P) {
    __shared__ float red[4];
    int rowid = blockIdx.x;
    int b = rowid >> 11, t = rowid & (TT - 1);
    const float* Sr = S + (size_t)b * TT * TT + (size_t)t * TT;
    f16* Pr = P + (size_t)b * TT * TT + (size_t)t * TT;
    int tid = threadIdx.x;
    int nv = t + 1;
    int rowend = ((t >> 7) + 1) << 7;
    float m = -3.0e38f;
    for (int c = tid; c < nv; c += 256) m = fmaxf(m, Sr[c]);
#pragma unroll
    for (int o = 32; o > 0; o >>= 1) m = fmaxf(m, __shfl_xor(m, o));
    if ((tid & 63) == 0) red[tid >> 6] = m;
    __syncthreads();
    m = fmaxf(fmaxf(red[0], red[1]), fmaxf(red[2], red[3]));
    __syncthreads();
    float s = 0.f;
    for (int c = tid; c < nv; c += 256) s += exp2f((Sr[c] - m) * L2E);
#pragma unroll
    for (int o = 32; o > 0; o >>= 1) s += __shfl_xor(s, o);
    if ((tid & 63) == 0) red[tid >> 6] = s;
    __syncthreads();
    s = red[0] + red[1] + red[2] + red[3];
    float inv = 1.0f / s;
    for (int c = tid; c < rowend; c += 256) {
        float p = (c < nv) ? exp2f((Sr[c] - m) * L2E) * inv : 0.0f;
        Pr[c] = (f16)p;
    }
}

__global__ __launch_bounds__(256, 2) void k2_pv(const f16* __restrict__ P,
                                                const float* __restrict__ V,
                                                float* __restrict__ O) {
    __shared__ f16 Pa[128][36];
    __shared__ f16 Vtt[128][36];
    int bid = blockIdx.x;
    int b = bid >> 7;
    int rest = bid & 127;
    int mi = rest >> 3, nj = rest & 7;
    int kend = (mi + 1) * 128;
    const f16* Pb = P + (size_t)b * TT * TT + (size_t)(mi * 128) * TT;
    const float* Vb = V + (size_t)b * TT * DD + nj * 128;
    float* Ob = O + (size_t)b * TT * DD + (size_t)(mi * 128) * DD + nj * 128;
    int tid = threadIdx.x;
    int lane = tid & 63;
    int wave = tid >> 6;
    int l31 = lane & 31, lhi = lane >> 5;
    int wrow = wave >> 1, wcol = wave & 1;
    f32x16 acc[2][2] = {};
    int pr = tid >> 1, pc = (tid & 1) * 16;
    int vk = tid >> 3, vn = (tid & 7) * 16;
    uint2 pbuf[4];
    float4 vbuf[4];
#pragma unroll
    for (int j = 0; j < 4; ++j) {
        pbuf[j] = *(const uint2*)(Pb + (size_t)pr * TT + pc + 4 * j);
        vbuf[j] = *(const float4*)(Vb + (size_t)vk * DD + vn + 4 * j);
    }
    for (int ck = 0; ck < kend; ck += 32) {
        __syncthreads();
#pragma unroll
        for (int j = 0; j < 4; ++j) {
            *(uint2*)&Pa[pr][pc + 4 * j] = pbuf[j];
            float4 v = vbuf[j];
            float vv[4] = {v.x, v.y, v.z, v.w};
            int n0 = vn + 4 * j;
#pragma unroll
            for (int e = 0; e < 4; ++e) {
                int n = n0 + e;
                Vtt[n][vk ^ ((((unsigned)n >> 4) & 3) << 3)] = (f16)vv[e];
            }
        }
        __syncthreads();
        if (ck + 32 < kend) {
            int cn = ck + 32;
#pragma unroll
            for (int j = 0; j < 4; ++j) {
                pbuf[j] = *(const uint2*)(Pb + (size_t)pr * TT + cn + pc + 4 * j);
                vbuf[j] = *(const float4*)(Vb + (size_t)(cn + vk) * DD + vn + 4 * j);
            }
        }
#pragma unroll
        for (int ks = 0; ks < 2; ++ks) {
            int kb = ks * 16 + lhi * 8;
            half8v paf[2], vbf[2];
#pragma unroll
            for (int f = 0; f < 2; ++f) {
                paf[f] = ld_frag(&Pa[wrow * 64 + f * 32 + l31][kb]);
                int n = wcol * 64 + f * 32 + l31;
                int kbs = kb ^ ((((unsigned)n >> 4) & 3) << 3);
                vbf[f] = ld_frag(&Vtt[n][kbs]);
            }
#pragma unroll
            for (int fm = 0; fm < 2; ++fm)
#pragma unroll
                for (int fn = 0; fn < 2; ++fn)
                    acc[fm][fn] = __builtin_amdgcn_mfma_f32_32x32x16_f16(paf[fm], vbf[fn], acc[fm][fn], 0, 0, 0);
        }
    }
#pragma unroll
    for (int fm = 0; fm < 2; ++fm)
#pragma unroll
        for (int fn = 0; fn < 2; ++fn)
#pragma unroll
            for (int g = 0; g < 16; ++g) {
                int rr = (g & 3) + 8 * (g >> 2) + 4 * lhi;
                int row = wrow * 64 + fm * 32 + rr;
                int col = wcol * 64 + fn * 32 + l31;
                Ob[(size_t)row * DD + col] = acc[fm][fn][g];
            }
}

__global__ __launch_bounds__(256) void fa_fallback(const float* __restrict__ Q,
                                                   const float* __restrict__ Kmat,
                                                   const float* __restrict__ V,
                                                   float* __restrict__ O) {
    __shared__ float qs[DD];
    __shared__ float osum[DD];
    __shared__ float red[4];
    int rowid = blockIdx.x;
    int b = rowid >> 11, t = rowid & (TT - 1);
    const float* q = Q + ((size_t)b * TT + t) * DD;
    int tid = threadIdx.x;
    for (int j = tid; j < DD; j += 256) { qs[j] = q[j] * SCALE; osum[j] = 0.f; }
    __syncthreads();
    float m = -3.0e38f, l = 0.f;
    for (int s = 0; s <= t; ++s) {
        const float* kr = Kmat + ((size_t)b * TT + s) * DD;
        float part = 0.f;
#pragma unroll
        for (int j = 0; j < 4; ++j) part += qs[tid * 4 + j] * kr[tid * 4 + j];
#pragma unroll
        for (int o = 32; o > 0; o >>= 1) part += __shfl_xor(part, o);
        if ((tid & 63) == 0) red[tid >> 6] = part;
        __syncthreads();
        float dot = red[0] + red[1] + red[2] + red[3];
        float mn = fmaxf(m, dot);
        float f = exp2f((m - mn) * 1.44269504f);
        float e = exp2f((dot - mn) * 1.44269504f);
        l = l * f + e;
        const float* vr = V + ((size_t)b * TT + s) * DD;
#pragma unroll
        for (int j = 0; j < 4; ++j) {
            int c = tid * 4 + j;
            osum[c] = osum[c] * f + e * vr[c];
        }
        m = mn;
        __syncthreads();
    }
    float inv = 1.f / l;
    for (int j = tid; j < DD; j += 256) O[((size_t)b * TT + t) * DD + j] = osum[j] * inv;
}

extern "C" void kernel_launch(void* const* d_in, const int* in_sizes, int n_in,
                              void* d_out, int out_size, void* d_ws, size_t ws_size,
                              hipStream_t stream) {
    const float* Q = (const float*)d_in[0];
    const float* K = (const float*)d_in[1];
    const float* V = (const float*)d_in[2];
    float* O = (float*)d_out;

    const size_t MB = 1024 * 1024;
    // new path layout: Qt 32 | Kt 32 | Vt 16 | Pt 32 | stats 1  = 113 MiB
    const size_t QT_B = 32 * MB, KT_B = 32 * MB, VT_B = 16 * MB, PT_B = 32 * MB;
    const size_t NEED = QT_B + KT_B + VT_B + PT_B + 1 * MB;

    size_t sbytes = (size_t)BB * TT * TT * 4;
    size_t pbytes = (size_t)BB * TT * TT * 2;

    if (ws_size >= NEED) {
        f16* Qt = (f16*)d_ws;
        f16* Kt = (f16*)((char*)d_ws + QT_B);
        f16* Vt = (f16*)((char*)d_ws + QT_B + KT_B);
        f16* Pt = (f16*)((char*)d_ws + QT_B + KT_B + VT_B);
        float2* stats = (float2*)((char*)d_ws + QT_B + KT_B + VT_B + PT_B);
        hipLaunchKernelGGL(prep, dim3(3072), dim3(256), 0, stream, Q, K, V, Qt, Kt, Vt);
        hipLaunchKernelGGL(k1_qk9, dim3(BB * NTILE), dim3(256), 0, stream, Qt, Kt, Pt, stats);
        hipLaunchKernelGGL(k2_pv9, dim3(512), dim3(256), 0, stream, Pt, Vt, stats, O);
    } else if (ws_size >= sbytes + pbytes) {
        float* S = (float*)d_ws;
        f16* P = (f16*)((char*)d_ws + sbytes);
        hipLaunchKernelGGL(k1_qk, dim3(BB * NTILE), dim3(256), 0, stream, Q, K, S);
        hipLaunchKernelGGL(k1b_softmax, dim3(BB * TT), dim3(256), 0, stream, S, P);
        hipLaunchKernelGGL(k2_pv, dim3(BB * 16 * 8), dim3(256), 0, stream, P, V, O);
    } else {
        hipLaunchKernelGGL(fa_fallback, dim3(BB * TT), dim3(256), 0, stream, Q, K, V, O);
    }
}

// Round 10
// 160.567 us; speedup vs baseline: 1.0792x; 1.0792x over previous
//
#include <hip/hip_runtime.h>

#define BB 4
#define TT 2048
#define DD 1024
#define SCALE 32.0f
#define NTILE 136   // 128x128 lower-tri tiles per batch
#define L2E 1.4426950408889634f

typedef _Float16 f16;
typedef __attribute__((ext_vector_type(4))) _Float16 half4v;
typedef __attribute__((ext_vector_type(8))) _Float16 half8v;
typedef __attribute__((ext_vector_type(16))) float f32x16;

typedef const __attribute__((address_space(1))) unsigned int* gas_u32;
typedef __attribute__((address_space(3))) unsigned int* las_u32;

static __device__ inline void gload16(const void* g, void* l) {
    __builtin_amdgcn_global_load_lds((gas_u32)g, (las_u32)l, 16, 0, 0);
}

static __device__ inline half8v ld_frag(const f16* p) {
    half4v a = *(const half4v*)p;
    half4v b = *(const half4v*)(p + 4);
    half8v r;
    r[0] = a[0]; r[1] = a[1]; r[2] = a[2]; r[3] = a[3];
    r[4] = b[0]; r[5] = b[1]; r[6] = b[2]; r[7] = b[3];
    return r;
}

// ===========================================================================
// Slot-major granules (8 KiB each), conflict-free ds_read_b128 by design:
//   Qt/Kt granule (b, mi, ck16):  byte = s*2048 + r*16   (s 0-1 hi, 2-3 lo)
//   Pt granule (b, mi, ck32):     byte = s*2048 + r*16, k = ck*32+s*8+e
//   Vt granule (b, nj, ck32):     byte = s*2048 + n*16, k = ck*32+s*8+e
// Consecutive ck granules are contiguous (8192 B apart).
// ===========================================================================

// --- prep: merged repack(Q,K) + transpose(V) -------------------------------
__global__ __launch_bounds__(256) void prep(const float* __restrict__ Q,
                                            const float* __restrict__ K,
                                            const float* __restrict__ V,
                                            f16* __restrict__ Qt,
                                            f16* __restrict__ Kt,
                                            f16* __restrict__ Vt) {
    __shared__ char plds[33024];
    int bid = blockIdx.x;
    int tid = threadIdx.x;
    if (bid < 2048) {
        char* rl = plds;   // 32768 B: 4 consecutive ck16 granule images
        int which = bid >> 10, b = (bid >> 8) & 3, mi = (bid >> 4) & 15, ks4 = bid & 15;
        const float* src = which ? K : Q;
        f16* dst = which ? Kt : Qt;
        float sc = which ? 1.0f : SCALE;
        int r = tid >> 1, h = tid & 1;
        const float* p = src + ((size_t)(b * TT + mi * 128 + r)) * DD + ks4 * 64 + h * 32;
#pragma unroll
        for (int j = 0; j < 4; ++j) {
            float4 x0 = *(const float4*)(p + j * 8);
            float4 x1 = *(const float4*)(p + j * 8 + 4);
            float vv[8] = {x0.x, x0.y, x0.z, x0.w, x1.x, x1.y, x1.z, x1.w};
            half8v hi, lo;
#pragma unroll
            for (int e = 0; e < 8; ++e) {
                float x = vv[e] * sc;
                f16 hh = (f16)x;
                hi[e] = hh;
                lo[e] = (f16)(x - (float)hh);
            }
            int ckl = h * 2 + (j >> 1);
            int shalf = j & 1;
            *(half8v*)(rl + ckl * 8192 + shalf * 2048 + r * 16) = hi;
            *(half8v*)(rl + ckl * 8192 + (2 + shalf) * 2048 + r * 16) = lo;
        }
        __syncthreads();
        char* gout = (char*)dst + ((size_t)((b * 16 + mi) * 64 + ks4 * 4)) * 8192 + tid * 128;
#pragma unroll
        for (int q = 0; q < 8; ++q)
            *(float4*)(gout + q * 16) = *(float4*)(rl + tid * 128 + q * 16);
    } else {
        float (*Vs)[129] = (float(*)[129])plds;   // [64][129]
        int bid2 = bid - 2048;                    // 1024 blocks
        int b = bid2 >> 8, kb = (bid2 >> 3) & 31, nj = bid2 & 7;
        const float* src = V + ((size_t)(b * TT + kb * 64)) * DD + nj * 128;
#pragma unroll
        for (int it = 0; it < 8; ++it) {
            int f4 = it * 256 + tid;
            int row = f4 >> 5, c4 = f4 & 31;
            float4 x = *(const float4*)(src + (size_t)row * DD + c4 * 4);
            Vs[row][c4 * 4 + 0] = x.x;
            Vs[row][c4 * 4 + 1] = x.y;
            Vs[row][c4 * 4 + 2] = x.z;
            Vs[row][c4 * 4 + 3] = x.w;
        }
        __syncthreads();
#pragma unroll
        for (int qq = 0; qq < 4; ++qq) {
            int q = tid * 4 + qq;             // [ckl2][s4][n128]
            int ckl = q >> 9, s = (q >> 7) & 3, n = q & 127;
            half8v hv;
#pragma unroll
            for (int e = 0; e < 8; ++e) hv[e] = (f16)Vs[ckl * 32 + s * 8 + e][n];
            char* out = (char*)Vt + ((size_t)((b * 8 + nj) * 64 + kb * 2 + ckl)) * 8192
                        + s * 2048 + n * 16;
            *(half8v*)out = hv;
        }
    }
}

// --- K1: proven best (67.3 us; m97-structure ceiling for this shape) -------
__global__ __launch_bounds__(256, 3) void k1_qk3(const f16* __restrict__ Qt,
                                                 const f16* __restrict__ Kt,
                                                 float* __restrict__ S) {
    __shared__ char lds[32768];   // 2 bufs x (A 8K | B 8K)

    int bid0 = blockIdx.x;
    int bid = (bid0 & 7) * (BB * NTILE / 8) + (bid0 >> 3);   // XCD swizzle
    int b = bid / NTILE, rr0 = bid % NTILE;
    int mi = 0;
    while ((mi + 1) * (mi + 2) / 2 <= rr0) ++mi;
    int nj = rr0 - mi * (mi + 1) / 2;

    const char* Abase = (const char*)Qt + ((size_t)((b * 16 + mi) * 64)) * 8192;
    const char* Bbase = (const char*)Kt + ((size_t)((b * 16 + nj) * 64)) * 8192;
    float* Sb = S + (size_t)b * TT * TT + (size_t)(mi * 128) * TT + nj * 128;

    int tid = threadIdx.x;
    int lane = tid & 63;
    int wv = tid >> 6;
    int l31 = lane & 31, lhi = lane >> 5;
    int wrow = wv >> 1, wcol = wv & 1;

    int aoff[2], boff[2];
#pragma unroll
    for (int f = 0; f < 2; ++f) {
        int ra = wrow * 64 + f * 32 + l31;
        int rb = wcol * 64 + f * 32 + l31;
        aoff[f] = lhi * 2048 + ra * 16;
        boff[f] = lhi * 2048 + rb * 16;
    }
    int lane_go = wv * 2048 + lane * 16;
    int lane_lo = wv * 2048;

    f32x16 acc[2][2] = {};

#define K1_STAGE(CK, BUF)                                                       \
    {                                                                           \
        const char* ga = Abase + (size_t)(CK) * 8192 + lane_go;                 \
        const char* gb = Bbase + (size_t)(CK) * 8192 + lane_go;                 \
        char* la = lds + (BUF) * 16384 + lane_lo;                               \
        char* lb = la + 8192;                                                   \
        gload16(ga, la);                                                        \
        gload16(ga + 1024, la + 1024);                                          \
        gload16(gb, lb);                                                        \
        gload16(gb + 1024, lb + 1024);                                          \
    }

    K1_STAGE(0, 0);
    int cur = 0;
    for (int ck = 0; ck < 64; ++ck) {
        __syncthreads();                   // buf[cur] loaded; buf[cur^1] free
        if (ck + 1 < 64) K1_STAGE(ck + 1, cur ^ 1);
        const char* As = lds + cur * 16384;
        const char* Bs = As + 8192;
        half8v ah[2], al[2], bh[2], bl[2];
#pragma unroll
        for (int f = 0; f < 2; ++f) {
            ah[f] = *(const half8v*)(As + aoff[f]);
            al[f] = *(const half8v*)(As + aoff[f] + 4096);
            bh[f] = *(const half8v*)(Bs + boff[f]);
            bl[f] = *(const half8v*)(Bs + boff[f] + 4096);
        }
#pragma unroll
        for (int fm = 0; fm < 2; ++fm)
#pragma unroll
            for (int fn = 0; fn < 2; ++fn) {
                acc[fm][fn] = __builtin_amdgcn_mfma_f32_32x32x16_f16(ah[fm], bh[fn], acc[fm][fn], 0, 0, 0);
                acc[fm][fn] = __builtin_amdgcn_mfma_f32_32x32x16_f16(ah[fm], bl[fn], acc[fm][fn], 0, 0, 0);
                acc[fm][fn] = __builtin_amdgcn_mfma_f32_32x32x16_f16(al[fm], bh[fn], acc[fm][fn], 0, 0, 0);
            }
        cur ^= 1;
    }
#undef K1_STAGE
#pragma unroll
    for (int fm = 0; fm < 2; ++fm)
#pragma unroll
        for (int fn = 0; fn < 2; ++fn)
#pragma unroll
            for (int g = 0; g < 16; ++g) {
                int rr = (g & 3) + 8 * (g >> 2) + 4 * lhi;
                int row = wrow * 64 + fm * 32 + rr;
                int col = wcol * 64 + fn * 32 + l31;
                Sb[(size_t)row * TT + col] = acc[fm][fn][g];
            }
}

__global__ __launch_bounds__(256) void k1b3(const float* __restrict__ S,
                                            f16* __restrict__ Pt) {
    __shared__ float red[4];
    int rowid = blockIdx.x;
    int b = rowid >> 11, t = rowid & (TT - 1);
    const float* Sr = S + ((size_t)b * TT + t) * TT;
    int tid = threadIdx.x;
    int nv = t + 1;
    int mi = t >> 7, r = t & 127;
    int rowend = (mi + 1) << 7;
    int c = tid * 8;
    bool act = c < rowend;

    float v[8] = {0, 0, 0, 0, 0, 0, 0, 0};
    if (act) {
        float4 x0 = *(const float4*)(Sr + c);
        float4 x1 = *(const float4*)(Sr + c + 4);
        v[0] = x0.x; v[1] = x0.y; v[2] = x0.z; v[3] = x0.w;
        v[4] = x1.x; v[5] = x1.y; v[6] = x1.z; v[7] = x1.w;
    }

    float m = -3.0e38f;
    if (act) {
#pragma unroll
        for (int j = 0; j < 8; ++j)
            if (c + j < nv) m = fmaxf(m, v[j]);
    }
#pragma unroll
    for (int o = 32; o > 0; o >>= 1) m = fmaxf(m, __shfl_xor(m, o));
    if ((tid & 63) == 0) red[tid >> 6] = m;
    __syncthreads();
    m = fmaxf(fmaxf(red[0], red[1]), fmaxf(red[2], red[3]));
    __syncthreads();

    float e[8];
    float s = 0.f;
#pragma unroll
    for (int j = 0; j < 8; ++j) {
        e[j] = (act && c + j < nv) ? exp2f((v[j] - m) * L2E) : 0.0f;
        s += e[j];
    }
#pragma unroll
    for (int o = 32; o > 0; o >>= 1) s += __shfl_xor(s, o);
    if ((tid & 63) == 0) red[tid >> 6] = s;
    __syncthreads();
    s = red[0] + red[1] + red[2] + red[3];
    float inv = 1.0f / s;

    if (act) {
        half8v hv;
#pragma unroll
        for (int j = 0; j < 8; ++j) hv[j] = (f16)(e[j] * inv);
        int ck = c >> 5, sl = (c >> 3) & 3;
        char* dst = (char*)Pt + ((size_t)((b * 16 + mi) * 64 + ck)) * 8192
                    + sl * 2048 + r * 16;
        *(half8v*)dst = hv;
    }
}

// --- K2: BK=64, 64 KB dbuf, drain-0, grid 512, slot-major (0 conflicts) ----
__global__ __launch_bounds__(256, 2) void k2_pv8(const f16* __restrict__ Pt,
                                                 const f16* __restrict__ Vt,
                                                 float* __restrict__ O) {
    __shared__ char lds[65536];   // 2 bufs x (A 16K | B 16K)

    int bid0 = blockIdx.x;
    int bid = (bid0 & 7) * 64 + (bid0 >> 3);    // XCD swizzle (512 blocks)
    int b = bid >> 7, mi = (bid >> 3) & 15, nj = bid & 7;
    int kch = 2 * (mi + 1);                     // BK=64 chunks -> (mi+1)*128 cols

    const char* Abase = (const char*)Pt + ((size_t)((b * 16 + mi) * 64)) * 8192;
    const char* Bbase = (const char*)Vt + ((size_t)((b * 8 + nj) * 64)) * 8192;
    float* Ob = O + (size_t)b * TT * DD + (size_t)(mi * 128) * DD + nj * 128;

    int tid = threadIdx.x;
    int lane = tid & 63;
    int wv = tid >> 6;
    int l31 = lane & 31, lhi = lane >> 5;
    int wrow = wv >> 1, wcol = wv & 1;
    int lane16 = lane * 16;

    int arow[2], brow[2];
#pragma unroll
    for (int f = 0; f < 2; ++f) {
        arow[f] = (wrow * 64 + f * 32 + l31) * 16;
        brow[f] = (wcol * 64 + f * 32 + l31) * 16;
    }

    f32x16 acc[2][2] = {};

#define K2_STAGE(CK, BUF)                                                       \
    {                                                                           \
        const char* ga = Abase + (size_t)(CK) * 16384 + wv * 4096 + lane16;     \
        const char* gb = Bbase + (size_t)(CK) * 16384 + wv * 4096 + lane16;     \
        char* la = lds + (BUF) * 32768 + wv * 4096;                             \
        char* lb = la + 16384;                                                  \
        gload16(ga, la);                                                        \
        gload16(ga + 1024, la + 1024);                                          \
        gload16(ga + 2048, la + 2048);                                          \
        gload16(ga + 3072, la + 3072);                                          \
        gload16(gb, lb);                                                        \
        gload16(gb + 1024, lb + 1024);                                          \
        gload16(gb + 2048, lb + 2048);                                          \
        gload16(gb + 3072, lb + 3072);                                          \
    }

    K2_STAGE(0, 0);
    int cur = 0;
    for (int it = 0; it < kch; ++it) {
        __syncthreads();
        if (it + 1 < kch) K2_STAGE(it + 1, cur ^ 1);
        const char* As = lds + cur * 32768;
        const char* Bs = As + 16384;
#pragma unroll
        for (int j = 0; j < 4; ++j) {
            int slotbase = (j >> 1) * 8192 + ((j & 1) * 2 + lhi) * 2048;
            half8v a0 = *(const half8v*)(As + slotbase + arow[0]);
            half8v a1 = *(const half8v*)(As + slotbase + arow[1]);
            half8v b0 = *(const half8v*)(Bs + slotbase + brow[0]);
            half8v b1 = *(const half8v*)(Bs + slotbase + brow[1]);
            acc[0][0] = __builtin_amdgcn_mfma_f32_32x32x16_f16(a0, b0, acc[0][0], 0, 0, 0);
            acc[0][1] = __builtin_amdgcn_mfma_f32_32x32x16_f16(a0, b1, acc[0][1], 0, 0, 0);
            acc[1][0] = __builtin_amdgcn_mfma_f32_32x32x16_f16(a1, b0, acc[1][0], 0, 0, 0);
            acc[1][1] = __builtin_amdgcn_mfma_f32_32x32x16_f16(a1, b1, acc[1][1], 0, 0, 0);
        }
        cur ^= 1;
    }
#undef K2_STAGE
#pragma unroll
    for (int fm = 0; fm < 2; ++fm)
#pragma unroll
        for (int fn = 0; fn < 2; ++fn)
#pragma unroll
            for (int g = 0; g < 16; ++g) {
                int rr = (g & 3) + 8 * (g >> 2) + 4 * lhi;
                int row = wrow * 64 + fm * 32 + rr;
                int col = wcol * 64 + fn * 32 + l31;
                Ob[(size_t)row * DD + col] = acc[fm][fn][g];
            }
}

// ===========================================================================
// FALLBACK (ws >= 96 MiB): r1 kernels, proven correct
// ===========================================================================
__global__ __launch_bounds__(256, 2) void k1_qk(const float* __restrict__ Q,
                                                const float* __restrict__ Kmat,
                                                float* __restrict__ S) {
    __shared__ f16 Ah[128][36], Al[128][36], Bh[128][36], Bl[128][36];
    int bid = blockIdx.x;
    int b = bid / NTILE, r = bid % NTILE;
    int mi = 0;
    while ((mi + 1) * (mi + 2) / 2 <= r) ++mi;
    int nj = r - mi * (mi + 1) / 2;
    const float* Qb = Q + ((size_t)b * TT + (size_t)mi * 128) * DD;
    const float* Kb = Kmat + ((size_t)b * TT + (size_t)nj * 128) * DD;
    float* Sb = S + (size_t)b * TT * TT + (size_t)(mi * 128) * TT + nj * 128;
    int tid = threadIdx.x;
    int lane = tid & 63;
    int wave = tid >> 6;
    int l31 = lane & 31, lhi = lane >> 5;
    int wrow = wave >> 1, wcol = wave & 1;
    int r0 = tid >> 1;
    int c0 = (tid & 1) * 16;
    f32x16 acc[2][2] = {};
    float4 abuf[4], bbuf[4];
#pragma unroll
    for (int j = 0; j < 4; ++j) {
        abuf[j] = *(const float4*)(Qb + (size_t)r0 * DD + c0 + 4 * j);
        bbuf[j] = *(const float4*)(Kb + (size_t)r0 * DD + c0 + 4 * j);
    }
    for (int ch = 0; ch < DD / 32; ++ch) {
        __syncthreads();
#pragma unroll
        for (int j = 0; j < 4; ++j) {
            float4 a = abuf[j], bq = bbuf[j];
            float ax[4] = {a.x * SCALE, a.y * SCALE, a.z * SCALE, a.w * SCALE};
            float bx[4] = {bq.x, bq.y, bq.z, bq.w};
            half4v ahv, alv, bhv, blv;
#pragma unroll
            for (int e = 0; e < 4; ++e) {
                f16 h = (f16)ax[e];
                ahv[e] = h;
                alv[e] = (f16)(ax[e] - (float)h);
                f16 g = (f16)bx[e];
                bhv[e] = g;
                blv[e] = (f16)(bx[e] - (float)g);
            }
            *(half4v*)&Ah[r0][c0 + 4 * j] = ahv;
            *(half4v*)&Al[r0][c0 + 4 * j] = alv;
            *(half4v*)&Bh[r0][c0 + 4 * j] = bhv;
            *(half4v*)&Bl[r0][c0 + 4 * j] = blv;
        }
        __syncthreads();
        if (ch + 1 < DD / 32) {
            int ck = (ch + 1) * 32;
#pragma unroll
            for (int j = 0; j < 4; ++j) {
                abuf[j] = *(const float4*)(Qb + (size_t)r0 * DD + ck + c0 + 4 * j);
                bbuf[j] = *(const float4*)(Kb + (size_t)r0 * DD + ck + c0 + 4 * j);
            }
        }
#pragma unroll
        for (int ks = 0; ks < 2; ++ks) {
            int kb = ks * 16 + lhi * 8;
            half8v ahf[2], alf[2], bhf[2], blf[2];
#pragma unroll
            for (int f = 0; f < 2; ++f) {
                ahf[f] = ld_frag(&Ah[wrow * 64 + f * 32 + l31][kb]);
                alf[f] = ld_frag(&Al[wrow * 64 + f * 32 + l31][kb]);
                bhf[f] = ld_frag(&Bh[wcol * 64 + f * 32 + l31][kb]);
                blf[f] = ld_frag(&Bl[wcol * 64 + f * 32 + l31][kb]);
            }
#pragma unroll
            for (int fm = 0; fm < 2; ++fm)
#pragma unroll
                for (int fn = 0; fn < 2; ++fn) {
                    acc[fm][fn] = __builtin_amdgcn_mfma_f32_32x32x16_f16(ahf[fm], bhf[fn], acc[fm][fn], 0, 0, 0);
                    acc[fm][fn] = __builtin_amdgcn_mfma_f32_32x32x16_f16(ahf[fm], blf[fn], acc[fm][fn], 0, 0, 0);
                    acc[fm][fn] = __builtin_amdgcn_mfma_f32_32x32x16_f16(alf[fm], bhf[fn], acc[fm][fn], 0, 0, 0);
                }
        }
    }
#pragma unroll
    for (int fm = 0; fm < 2; ++fm)
#pragma unroll
        for (int fn = 0; fn < 2; ++fn)
#pragma unroll
            for (int g = 0; g < 16; ++g) {
                int rr = (g & 3) + 8 * (g >> 2) + 4 * lhi;
                int row = wrow * 64 + fm * 32 + rr;
                int col = wcol * 64 + fn * 32 + l31;
                Sb[(size_t)row * TT + col] = acc[fm][fn][g];
            }
}

__global__ __launch_bounds__(256) void k1b_softmax(const float* __restrict__ S,
                                                   f16* __restrict__ P) {
    __shared__ float red[4];
    int rowid = blockIdx.x;
    int b = rowid >> 11, t = rowid & (TT - 1);
    const float* Sr = S + (size_t)b * TT * TT + (size_t)t * TT;
    f16* Pr = P + (size_t)b * TT * TT + (size_t)t * TT;
    int tid = threadIdx.x;
    int nv = t + 1;
    int rowend = ((t >> 7) + 1) << 7;
    float m = -3.0e38f;
    for (int c = tid; c < nv; c += 256) m = fmaxf(m, Sr[c]);
#pragma unroll
    for (int o = 32; o > 0; o >>= 1) m = fmaxf(m, __shfl_xor(m, o));
    if ((tid & 63) == 0) red[tid >> 6] = m;
    __syncthreads();
    m = fmaxf(fmaxf(red[0], red[1]), fmaxf(red[2], red[3]));
    __syncthreads();
    float s = 0.f;
    for (int c = tid; c < nv; c += 256) s += exp2f((Sr[c] - m) * L2E);
#pragma unroll
    for (int o = 32; o > 0; o >>= 1) s += __shfl_xor(s, o);
    if ((tid & 63) == 0) red[tid >> 6] = s;
    __syncthreads();
    s = red[0] + red[1] + red[2] + red[3];
    float inv = 1.0f / s;
    for (int c = tid; c < rowend; c += 256) {
        float p = (c < nv) ? exp2f((Sr[c] - m) * L2E) * inv : 0.0f;
        Pr[c] = (f16)p;
    }
}

__global__ __launch_bounds__(256, 2) void k2_pv(const f16* __restrict__ P,
                                                const float* __restrict__ V,
                                                float* __restrict__ O) {
    __shared__ f16 Pa[128][36];
    __shared__ f16 Vtt[128][36];
    int bid = blockIdx.x;
    int b = bid >> 7;
    int rest = bid & 127;
    int mi = rest >> 3, nj = rest & 7;
    int kend = (mi + 1) * 128;
    const f16* Pb = P + (size_t)b * TT * TT + (size_t)(mi * 128) * TT;
    const float* Vb = V + (size_t)b * TT * DD + nj * 128;
    float* Ob = O + (size_t)b * TT * DD + (size_t)(mi * 128) * DD + nj * 128;
    int tid = threadIdx.x;
    int lane = tid & 63;
    int wave = tid >> 6;
    int l31 = lane & 31, lhi = lane >> 5;
    int wrow = wave >> 1, wcol = wave & 1;
    f32x16 acc[2][2] = {};
    int pr = tid >> 1, pc = (tid & 1) * 16;
    int vk = tid >> 3, vn = (tid & 7) * 16;
    uint2 pbuf[4];
    float4 vbuf[4];
#pragma unroll
    for (int j = 0; j < 4; ++j) {
        pbuf[j] = *(const uint2*)(Pb + (size_t)pr * TT + pc + 4 * j);
        vbuf[j] = *(const float4*)(Vb + (size_t)vk * DD + vn + 4 * j);
    }
    for (int ck = 0; ck < kend; ck += 32) {
        __syncthreads();
#pragma unroll
        for (int j = 0; j < 4; ++j) {
            *(uint2*)&Pa[pr][pc + 4 * j] = pbuf[j];
            float4 v = vbuf[j];
            float vv[4] = {v.x, v.y, v.z, v.w};
            int n0 = vn + 4 * j;
#pragma unroll
            for (int e = 0; e < 4; ++e) {
                int n = n0 + e;
                Vtt[n][vk ^ ((((unsigned)n >> 4) & 3) << 3)] = (f16)vv[e];
            }
        }
        __syncthreads();
        if (ck + 32 < kend) {
            int cn = ck + 32;
#pragma unroll
            for (int j = 0; j < 4; ++j) {
                pbuf[j] = *(const uint2*)(Pb + (size_t)pr * TT + cn + pc + 4 * j);
                vbuf[j] = *(const float4*)(Vb + (size_t)(cn + vk) * DD + vn + 4 * j);
            }
        }
#pragma unroll
        for (int ks = 0; ks < 2; ++ks) {
            int kb = ks * 16 + lhi * 8;
            half8v paf[2], vbf[2];
#pragma unroll
            for (int f = 0; f < 2; ++f) {
                paf[f] = ld_frag(&Pa[wrow * 64 + f * 32 + l31][kb]);
                int n = wcol * 64 + f * 32 + l31;
                int kbs = kb ^ ((((unsigned)n >> 4) & 3) << 3);
                vbf[f] = ld_frag(&Vtt[n][kbs]);
            }
#pragma unroll
            for (int fm = 0; fm < 2; ++fm)
#pragma unroll
                for (int fn = 0; fn < 2; ++fn)
                    acc[fm][fn] = __builtin_amdgcn_mfma_f32_32x32x16_f16(paf[fm], vbf[fn], acc[fm][fn], 0, 0, 0);
        }
    }
#pragma unroll
    for (int fm = 0; fm < 2; ++fm)
#pragma unroll
        for (int fn = 0; fn < 2; ++fn)
#pragma unroll
            for (int g = 0; g < 16; ++g) {
                int rr = (g & 3) + 8 * (g >> 2) + 4 * lhi;
                int row = wrow * 64 + fm * 32 + rr;
                int col = wcol * 64 + fn * 32 + l31;
                Ob[(size_t)row * DD + col] = acc[fm][fn][g];
            }
}

__global__ __launch_bounds__(256) void fa_fallback(const float* __restrict__ Q,
                                                   const float* __restrict__ Kmat,
                                                   const float* __restrict__ V,
                                                   float* __restrict__ O) {
    __shared__ float qs[DD];
    __shared__ float osum[DD];
    __shared__ float red[4];
    int rowid = blockIdx.x;
    int b = rowid >> 11, t = rowid & (TT - 1);
    const float* q = Q + ((size_t)b * TT + t) * DD;
    int tid = threadIdx.x;
    for (int j = tid; j < DD; j += 256) { qs[j] = q[j] * SCALE; osum[j] = 0.f; }
    __syncthreads();
    float m = -3.0e38f, l = 0.f;
    for (int s = 0; s <= t; ++s) {
        const float* kr = Kmat + ((size_t)b * TT + s) * DD;
        float part = 0.f;
#pragma unroll
        for (int j = 0; j < 4; ++j) part += qs[tid * 4 + j] * kr[tid * 4 + j];
#pragma unroll
        for (int o = 32; o > 0; o >>= 1) part += __shfl_xor(part, o);
        if ((tid & 63) == 0) red[tid >> 6] = part;
        __syncthreads();
        float dot = red[0] + red[1] + red[2] + red[3];
        float mn = fmaxf(m, dot);
        float f = exp2f((m - mn) * 1.44269504f);
        float e = exp2f((dot - mn) * 1.44269504f);
        l = l * f + e;
        const float* vr = V + ((size_t)b * TT + s) * DD;
#pragma unroll
        for (int j = 0; j < 4; ++j) {
            int c = tid * 4 + j;
            osum[c] = osum[c] * f + e * vr[c];
        }
        m = mn;
        __syncthreads();
    }
    float inv = 1.f / l;
    for (int j = tid; j < DD; j += 256) O[((size_t)b * TT + t) * DD + j] = osum[j] * inv;
}

extern "C" void kernel_launch(void* const* d_in, const int* in_sizes, int n_in,
                              void* d_out, int out_size, void* d_ws, size_t ws_size,
                              hipStream_t stream) {
    const float* Q = (const float*)d_in[0];
    const float* K = (const float*)d_in[1];
    const float* V = (const float*)d_in[2];
    float* O = (float*)d_out;

    const size_t MB = 1024 * 1024;
    const size_t QT_B = 32 * MB, KT_B = 32 * MB, VT_B = 16 * MB, S_B = 64 * MB;
    const size_t FULL = QT_B + KT_B + VT_B + S_B;   // 144 MiB (Pt aliases Qt)

    size_t sbytes = (size_t)BB * TT * TT * 4;
    size_t pbytes = (size_t)BB * TT * TT * 2;

    if (ws_size >= FULL) {
        f16* Qt = (f16*)d_ws;
        f16* Kt = (f16*)((char*)d_ws + QT_B);
        f16* Vt = (f16*)((char*)d_ws + QT_B + KT_B);
        float* S = (float*)((char*)d_ws + QT_B + KT_B + VT_B);
        f16* Pt = (f16*)d_ws;   // aliases Qt (dead after k1)
        hipLaunchKernelGGL(prep, dim3(3072), dim3(256), 0, stream, Q, K, V, Qt, Kt, Vt);
        hipLaunchKernelGGL(k1_qk3, dim3(BB * NTILE), dim3(256), 0, stream, Qt, Kt, S);
        hipLaunchKernelGGL(k1b3, dim3(BB * TT), dim3(256), 0, stream, S, Pt);
        hipLaunchKernelGGL(k2_pv8, dim3(512), dim3(256), 0, stream, Pt, Vt, O);
    } else if (ws_size >= sbytes + pbytes) {
        float* S = (float*)d_ws;
        f16* P = (f16*)((char*)d_ws + sbytes);
        hipLaunchKernelGGL(k1_qk, dim3(BB * NTILE), dim3(256), 0, stream, Q, K, S);
        hipLaunchKernelGGL(k1b_softmax, dim3(BB * TT), dim3(256), 0, stream, S, P);
        hipLaunchKernelGGL(k2_pv, dim3(BB * 16 * 8), dim3(256), 0, stream, P, V, O);
    } else {
        hipLaunchKernelGGL(fa_fallback, dim3(BB * TT), dim3(256), 0, stream, Q, K, V, O);
    }
}